// Round 2
// baseline (188.248 us; speedup 1.0000x reference)
//
#include <hip/hip_runtime.h>
#include <stdint.h>

// Problem: input (4, 200, 64, 64, 8) fp32. Per neuron (b,h,w,c), per 100-step
// chunk: acc += x[t]; if (acc > 2) { spike=1; acc=0; }  (bit-exact vs reference
// peel loop). Output out[b,t,w,c,h] = spike as fp32.
#define BDIM   4
#define TTOT   200
#define CHUNK  100
#define HWC    32768            // 64*64*8 floats per (b,t) plane
#define NREG   (BDIM * TTOT)    // 800 (b,t) regions
#define RS_WS  32768u           // spike-region stride (bytes) in workspace
#define RS_IP  131072u          // spike-region stride (bytes) aliased over d_out

// ---------------- Kernel 1: integrate-and-fire scan ----------------
// 131072 threads; thread = (chunk, b, even-neuron i). float2 loads (coalesced
// 512 B/wave), uchar2 spike stores (128 B/wave contiguous).
__global__ __launch_bounds__(256) void spike_kernel(const float* __restrict__ x,
                                                    uint8_t* __restrict__ spk,
                                                    unsigned rstride) {
    unsigned g     = blockIdx.x * 256u + threadIdx.x;   // [0, 131072)
    unsigned chunk = g >> 16;
    unsigned p     = g & 65535u;
    unsigned b     = p >> 14;                            // 16384 pairs per b
    unsigned i     = (p & 16383u) * 2u;
    unsigned t0    = b * TTOT + chunk * CHUNK;

    const float2* xp = (const float2*)(x + (size_t)t0 * HWC + i);
    uint8_t*      sp = spk + (size_t)t0 * rstride + i;

    float a0 = 0.0f, a1 = 0.0f;
    for (int tb = 0; tb < CHUNK; tb += 4) {
        float2 v[4];
#pragma unroll
        for (int k = 0; k < 4; ++k) v[k] = xp[(size_t)k * (HWC / 2)];
        xp += 4 * (HWC / 2);
#pragma unroll
        for (int k = 0; k < 4; ++k) {
            a0 += v[k].x; a1 += v[k].y;
            unsigned s0 = 0u, s1 = 0u;
            if (a0 > 2.0f) { s0 = 1u; a0 = 0.0f; }
            if (a1 > 2.0f) { s1 = 1u; a1 = 0.0f; }
            *(uint16_t*)sp = (uint16_t)(s0 | (s1 << 8));
            sp += rstride;
        }
    }
}

// ---------------- Kernel 2a (workspace): half-region transpose ----------------
// 1600 blocks x 256. Block = (region, wc-half). Stage 16 KB (64 h-rows x 256 B)
// into padded LDS, emit 64 KB fully contiguous fp32. LDS reads: 4-lane u32
// broadcast + byte extract -> 2-way bank aliasing (free).
__global__ __launch_bounds__(256) void transpose_ws(const uint8_t* __restrict__ spk,
                                                    float* __restrict__ out) {
    __shared__ uint32_t lds[64 * 65];       // row pad 64->65 u32
    unsigned blk = blockIdx.x;
    unsigned region = blk >> 1, half = blk & 1u;
    unsigned tid = threadIdx.x;

    const uint32_t* in32 = (const uint32_t*)(spk + (size_t)region * RS_WS);
#pragma unroll
    for (int it = 0; it < 16; ++it) {
        unsigned idx = it * 256u + tid;     // [0, 4096)
        unsigned h = idx >> 6, wq = idx & 63u;
        lds[h * 65u + wq] = in32[h * 128u + half * 64u + wq];
    }
    __syncthreads();

    float4* out4 = (float4*)out + (size_t)region * 8192u + half * 4096u;
#pragma unroll
    for (int it = 0; it < 16; ++it) {
        unsigned f   = it * 256u + tid;     // [0, 4096) -> contiguous stores
        unsigned wcl = f >> 4;              // local wc in [0,256)
        unsigned h0  = (f & 15u) << 2;
        unsigned wq  = wcl >> 2, sel = (wcl & 3u) * 8u;
        float4 v;
        v.x = (float)((lds[(h0 + 0u) * 65u + wq] >> sel) & 1u);
        v.y = (float)((lds[(h0 + 1u) * 65u + wq] >> sel) & 1u);
        v.z = (float)((lds[(h0 + 2u) * 65u + wq] >> sel) & 1u);
        v.w = (float)((lds[(h0 + 3u) * 65u + wq] >> sel) & 1u);
        out4[f] = v;
    }
}

// ---------------- Kernel 2b (fallback, in-place over d_out) ----------------
// 800 blocks x 512; one block per region (read-before-overwrite safe via
// __syncthreads). Same broadcast-read scheme, pad 128->129.
__global__ __launch_bounds__(512) void transpose_ip(float* __restrict__ out) {
    __shared__ uint32_t lds[64 * 129];
    unsigned region = blockIdx.x;
    unsigned tid = threadIdx.x;

    const uint32_t* in32 = (const uint32_t*)((const uint8_t*)out + (size_t)region * RS_IP);
#pragma unroll
    for (int it = 0; it < 16; ++it) {
        unsigned idx = it * 512u + tid;     // [0, 8192)
        unsigned h = idx >> 7, wq = idx & 127u;
        lds[h * 129u + wq] = in32[idx];
    }
    __syncthreads();

    float4* out4 = (float4*)out + (size_t)region * 8192u;
#pragma unroll
    for (int it = 0; it < 16; ++it) {
        unsigned f  = it * 512u + tid;      // [0, 8192)
        unsigned wc = f >> 4;               // [0, 512)
        unsigned h0 = (f & 15u) << 2;
        unsigned wq = wc >> 2, sel = (wc & 3u) * 8u;
        float4 v;
        v.x = (float)((lds[(h0 + 0u) * 129u + wq] >> sel) & 1u);
        v.y = (float)((lds[(h0 + 1u) * 129u + wq] >> sel) & 1u);
        v.z = (float)((lds[(h0 + 2u) * 129u + wq] >> sel) & 1u);
        v.w = (float)((lds[(h0 + 3u) * 129u + wq] >> sel) & 1u);
        out4[f] = v;
    }
}

extern "C" void kernel_launch(void* const* d_in, const int* in_sizes, int n_in,
                              void* d_out, int out_size, void* d_ws, size_t ws_size,
                              hipStream_t stream) {
    (void)in_sizes; (void)n_in; (void)out_size;
    const float* x = (const float*)d_in[0];
    float* out = (float*)d_out;

    const size_t spike_bytes = (size_t)NREG * RS_WS;   // 26.2 MB
    if (ws_size >= spike_bytes) {
        uint8_t* spk = (uint8_t*)d_ws;
        hipLaunchKernelGGL(spike_kernel, dim3(512), dim3(256), 0, stream, x, spk, RS_WS);
        hipLaunchKernelGGL(transpose_ws, dim3(2 * NREG), dim3(256), 0, stream, spk, out);
    } else {
        hipLaunchKernelGGL(spike_kernel, dim3(512), dim3(256), 0, stream, x, (uint8_t*)out, RS_IP);
        hipLaunchKernelGGL(transpose_ip, dim3(NREG), dim3(512), 0, stream, out);
    }
}

// Round 3
// 182.016 us; speedup vs baseline: 1.0342x; 1.0342x over previous
//
#include <hip/hip_runtime.h>
#include <stdint.h>

// Input (4, 200, 64, 64, 8) fp32. Per neuron (b,h,w,c), per 100-step chunk:
// acc += x[t]; if (acc > 2) { spike = 1; acc = 0; }   (bit-exact vs reference)
// Output out[b,t,w,c,h] = spike (fp32).
//
// Pipeline: K1 packs spikes as BITS -> 4 MB intermediate (vs 26 MB as bytes),
// planar layout spk[slab][tw][neuron] (slab = b*2+chunk, tw = t/32).
// K2 expands bits -> fp32 in output order with fully contiguous float4 stores.
#define HWC    32768           // 64*64*8 neurons per (b,t) plane
#define NSLAB  8               // 4 b x 2 chunks
#define TTOT   200
#define CHUNK  100

// ---------------- K1: bit-packed integrate-and-fire scan ----------------
// 262144 threads (1024 x 256); thread = (slab, neuron). Coalesced dword loads
// (8-batched for MLP), compile-time bit positions, 4 coalesced stores at end.
__global__ __launch_bounds__(256) void spike_bits(const float* __restrict__ x,
                                                  uint32_t* __restrict__ spk) {
    unsigned g    = blockIdx.x * 256u + threadIdx.x;   // [0, 262144)
    unsigned slab = g >> 15;                           // [0, 8)
    unsigned n    = g & (HWC - 1);
    unsigned b    = slab >> 1, ch = slab & 1u;
    const float* xp = x + (size_t)(b * TTOT + ch * CHUNK) * HWC + n;

    float acc = 0.0f;
    uint32_t w0 = 0u, w1 = 0u, w2 = 0u, w3 = 0u;
    uint32_t* wsel[1]; (void)wsel;

#define STEP(WREG, TB, K)                                         \
    do {                                                          \
        acc += v[K];                                              \
        if (acc > 2.0f) { WREG |= (1u << ((TB) + (K))); acc = 0.0f; } \
    } while (0)

#define GROUP8(WREG, TBASE)                                       \
    do {                                                          \
        float v[8];                                               \
        _Pragma("unroll")                                         \
        for (int k = 0; k < 8; ++k) v[k] = xp[(size_t)((TBASE) + k) * HWC]; \
        STEP(WREG, (TBASE) & 31, 0); STEP(WREG, (TBASE) & 31, 1); \
        STEP(WREG, (TBASE) & 31, 2); STEP(WREG, (TBASE) & 31, 3); \
        STEP(WREG, (TBASE) & 31, 4); STEP(WREG, (TBASE) & 31, 5); \
        STEP(WREG, (TBASE) & 31, 6); STEP(WREG, (TBASE) & 31, 7); \
    } while (0)

    GROUP8(w0,  0); GROUP8(w0,  8); GROUP8(w0, 16); GROUP8(w0, 24);
    GROUP8(w1, 32); GROUP8(w1, 40); GROUP8(w1, 48); GROUP8(w1, 56);
    GROUP8(w2, 64); GROUP8(w2, 72); GROUP8(w2, 80); GROUP8(w2, 88);
    {   // t = 96..99
        float v[4];
#pragma unroll
        for (int k = 0; k < 4; ++k) v[k] = xp[(size_t)(96 + k) * HWC];
        STEP(w3, 0, 0); STEP(w3, 0, 1); STEP(w3, 0, 2); STEP(w3, 0, 3);
    }
#undef GROUP8
#undef STEP

    uint32_t* sp = spk + ((size_t)slab << 17);   // slab stride = 4*HWC u32
    sp[n]            = w0;
    sp[HWC + n]      = w1;
    sp[2u * HWC + n] = w2;
    sp[3u * HWC + n] = w3;
}

// ---------------- K2: bit expand + transpose ----------------
// 512 blocks x 512 threads; block = (slab, t-quarter q of 25 steps, wc-tile of
// 32). Stages the two bit-planes touched by its t-range (2 x 8 KB, padded LDS,
// 2-way aliasing = free), hoists 8 words/thread to registers, then 25 fully
// contiguous 8 KB float4 stores.
__global__ __launch_bounds__(512) void expand_bits(const uint32_t* __restrict__ spk,
                                                   float* __restrict__ out) {
    __shared__ uint32_t lds[2 * 2112];           // 2 planes x 64h x 33 (pad)
    unsigned gid  = blockIdx.x;                  // [0, 512)
    unsigned slab = gid >> 6;
    unsigned q    = (gid >> 4) & 3u;
    unsigned tile = gid & 15u;
    unsigned wc0  = tile * 32u;
    unsigned t0   = q * 25u;
    unsigned p0   = t0 >> 5;                     // first bit-plane (0,0,1,2)
    unsigned p1   = (t0 + 24u) >> 5;             // second bit-plane (0,1,2,3)
    unsigned tid  = threadIdx.x;

    const uint32_t* sbase = spk + ((size_t)slab << 17);
#pragma unroll
    for (int it = 0; it < 8; ++it) {
        unsigned idx = it * 512u + tid;          // [0, 4096)
        unsigned pl  = idx >> 11;                // 0 / 1
        unsigned r   = idx & 2047u;
        unsigned h   = r >> 5, wcl = r & 31u;
        unsigned tw  = pl ? p1 : p0;
        lds[pl * 2112u + h * 33u + wcl] =
            sbase[((size_t)tw << 15) + h * 512u + wc0 + wcl];
    }
    __syncthreads();

    unsigned wcl = tid >> 4;                     // [0, 32)
    unsigned h0  = (tid & 15u) * 4u;             // 0,4,...,60
    uint32_t r0[4], r1[4];
#pragma unroll
    for (int k = 0; k < 4; ++k) {                // 2-way bank aliasing (free)
        r0[k] = lds[(h0 + k) * 33u + wcl];
        r1[k] = lds[2112u + (h0 + k) * 33u + wcl];
    }

    unsigned b = slab >> 1, ch = slab & 1u;
    unsigned rbase = b * TTOT + ch * CHUNK;      // output region index base
    float4* o4 = (float4*)out;

#pragma unroll
    for (int j = 0; j < 25; ++j) {
        unsigned t   = t0 + j;
        unsigned sel = (t >> 5) != p0;           // wave-uniform
        unsigned bit = t & 31u;
        uint32_t a0 = sel ? r1[0] : r0[0];
        uint32_t a1 = sel ? r1[1] : r0[1];
        uint32_t a2 = sel ? r1[2] : r0[2];
        uint32_t a3 = sel ? r1[3] : r0[3];
        float4 v;
        v.x = (float)((a0 >> bit) & 1u);
        v.y = (float)((a1 >> bit) & 1u);
        v.z = (float)((a2 >> bit) & 1u);
        v.w = (float)((a3 >> bit) & 1u);
        // region (rbase+t): 8192 float4; tile chunk wc0*16; contiguous per t
        o4[(size_t)(rbase + t) * 8192u + wc0 * 16u + tid] = v;
    }
}

// ---------------- Fallback (ws too small): R2 in-place scheme ----------------
__global__ __launch_bounds__(256) void spike_kernel_ip(const float* __restrict__ x,
                                                       uint8_t* __restrict__ spk) {
    unsigned g     = blockIdx.x * 256u + threadIdx.x;
    unsigned chunk = g >> 16;
    unsigned p     = g & 65535u;
    unsigned b     = p >> 14;
    unsigned i     = (p & 16383u) * 2u;
    unsigned t0    = b * TTOT + chunk * CHUNK;
    const float2* xp = (const float2*)(x + (size_t)t0 * HWC + i);
    uint8_t*      sp = spk + (size_t)t0 * 131072u + i;
    float a0 = 0.0f, a1 = 0.0f;
    for (int tb = 0; tb < CHUNK; tb += 4) {
        float2 v[4];
#pragma unroll
        for (int k = 0; k < 4; ++k) v[k] = xp[(size_t)k * (HWC / 2)];
        xp += 4 * (HWC / 2);
#pragma unroll
        for (int k = 0; k < 4; ++k) {
            a0 += v[k].x; a1 += v[k].y;
            unsigned s0 = 0u, s1 = 0u;
            if (a0 > 2.0f) { s0 = 1u; a0 = 0.0f; }
            if (a1 > 2.0f) { s1 = 1u; a1 = 0.0f; }
            *(uint16_t*)sp = (uint16_t)(s0 | (s1 << 8));
            sp += 131072u;
        }
    }
}

__global__ __launch_bounds__(512) void transpose_ip(float* __restrict__ out) {
    __shared__ uint32_t lds[64 * 129];
    unsigned region = blockIdx.x;
    unsigned tid = threadIdx.x;
    const uint32_t* in32 = (const uint32_t*)((const uint8_t*)out + (size_t)region * 131072u);
#pragma unroll
    for (int it = 0; it < 16; ++it) {
        unsigned idx = it * 512u + tid;
        unsigned h = idx >> 7, wq = idx & 127u;
        lds[h * 129u + wq] = in32[idx];
    }
    __syncthreads();
    float4* out4 = (float4*)out + (size_t)region * 8192u;
#pragma unroll
    for (int it = 0; it < 16; ++it) {
        unsigned f  = it * 512u + tid;
        unsigned wc = f >> 4;
        unsigned h0 = (f & 15u) << 2;
        unsigned wq = wc >> 2, sel = (wc & 3u) * 8u;
        float4 v;
        v.x = (float)((lds[(h0 + 0u) * 129u + wq] >> sel) & 1u);
        v.y = (float)((lds[(h0 + 1u) * 129u + wq] >> sel) & 1u);
        v.z = (float)((lds[(h0 + 2u) * 129u + wq] >> sel) & 1u);
        v.w = (float)((lds[(h0 + 3u) * 129u + wq] >> sel) & 1u);
        out4[f] = v;
    }
}

extern "C" void kernel_launch(void* const* d_in, const int* in_sizes, int n_in,
                              void* d_out, int out_size, void* d_ws, size_t ws_size,
                              hipStream_t stream) {
    (void)in_sizes; (void)n_in; (void)out_size;
    const float* x = (const float*)d_in[0];
    float* out = (float*)d_out;

    const size_t bit_bytes = (size_t)NSLAB * 4u * HWC * 4u;   // 4 MB
    if (ws_size >= bit_bytes) {
        uint32_t* spk = (uint32_t*)d_ws;
        hipLaunchKernelGGL(spike_bits, dim3(1024), dim3(256), 0, stream, x, spk);
        hipLaunchKernelGGL(expand_bits, dim3(512), dim3(512), 0, stream, spk, out);
    } else {
        hipLaunchKernelGGL(spike_kernel_ip, dim3(512), dim3(256), 0, stream, x, (uint8_t*)out);
        hipLaunchKernelGGL(transpose_ip, dim3(NSLAB * CHUNK), dim3(512), 0, stream, out);
    }
}